// Round 19
// baseline (372.408 us; speedup 1.0000x reference)
//
#include <hip/hip_runtime.h>
#include <hip/hip_bf16.h>
#include <stdint.h>

// Problem constants: E=512, H=8, hd=64, T=1024, B=16, N=B*H=128, S=1025
typedef __bf16 bf16;
typedef __bf16 bf16x8 __attribute__((ext_vector_type(8)));
typedef __bf16 bf16x4 __attribute__((ext_vector_type(4)));
typedef __bf16 bf16x2 __attribute__((ext_vector_type(2)));
typedef float  f32x4  __attribute__((ext_vector_type(4)));

#define MFMA_BF16(a,b,c) __builtin_amdgcn_mfma_f32_16x16x32_bf16((a),(b),(c),0,0,0)

// ---- workspace byte offsets (total ~104.4 MB) ----
#define WS_QBF_IN  0L            // 16777216  query bf16 [r=(t,b)][e]   (reused as A2 later)
#define WS_WBF     16777216L     // 1572864   mutated in_proj_weight bf16 [f][e]
#define WS_OUTWBF  18350080L     // 524288    out_w bf16 [e][e']
#define WS_Q       18874368L     // 16777216  q*0.125 bf16 [n][t][d]
#define WS_K       35651584L     // 16777216  k bf16 [n][s<1024][d]
#define WS_V       52428800L     // 16777216  v bf16 [n][s<1024][d]; + vT = 33.5MB contig,
                                 //           reused as aw_raw bf16 [b][t][s<1024] after ktv
#define WS_VT      69206016L     // 16777216  v^T bf16 [n][d][s<1024]
#define WS_AWLAST  85983232L     // 524288    fp32 aw[:, :, 1024] as [n][t]
#define WS_VCS     86507520L     // 32768     fp32 col-sum of v (incl bias row) [n][d]
#define WS_MM      86540288L     // 8         {min,max} ordered-uint
#define WS_KT      86540544L     // 16777216  k^T bf16 [n][d][s<1024]
#define WS_KTV     103317760L    // 1048576   (K^T V)^T bf16 [n][d'][d]

__device__ __forceinline__ void gload16(const void* g, void* l) {
  __builtin_amdgcn_global_load_lds((const __attribute__((address_space(1))) uint32_t*)g,
                                   (__attribute__((address_space(3))) uint32_t*)l, 16, 0, 0);
}
__device__ __forceinline__ unsigned ordf(float x) {
  unsigned b = __float_as_uint(x);
  return (b & 0x80000000u) ? ~b : (b | 0x80000000u);
}
__device__ __forceinline__ float deordf(unsigned u) {
  unsigned b = (u & 0x80000000u) ? (u ^ 0x80000000u) : ~u;
  return __uint_as_float(b);
}

// ---------------- merged prep: query cvt + weight mutation/convert + w_ret ----------------
__global__ __launch_bounds__(256) void prep_all_kernel(
    const float* __restrict__ query, bf16* __restrict__ qbf_out,
    const float* __restrict__ in_w, const float* __restrict__ i_proj,
    const float* __restrict__ out_w, bf16* __restrict__ w_bf,
    bf16* __restrict__ outw_bf, float* __restrict__ w_ret,
    unsigned* __restrict__ mm) {
  long idx = (long)blockIdx.x * 256 + threadIdx.x;   // grid 4096 -> 0..1048575
  if (idx == 0) { mm[0] = 0xFFFFFFFFu; mm[1] = 0u; } // min-slot, max-slot
  if (idx < 786432L) {
    int f = (int)(idx >> 9), e = (int)(idx & 511);
    float val = (e % 3 == 0) ? i_proj[f] : in_w[idx];
    w_bf[idx] = (bf16)val;
    w_ret[(long)(f >> 9) * 262144 + (long)e * 512 + (f & 511)] = val;   // w_ret[m][e][f%512]
  } else if (idx < 1048576L) {
    long j = idx - 786432L;
    outw_bf[j] = (bf16)out_w[j];
  }
  // query cvt: 2097152 float4s, 2 per thread
#pragma unroll
  for (int it = 0; it < 2; ++it) {
    long i = idx + (long)it * 1048576L;
    float4 v = ((const float4*)query)[i];
    bf16x4 o; o[0] = (bf16)v.x; o[1] = (bf16)v.y; o[2] = (bf16)v.z; o[3] = (bf16)v.w;
    ((bf16x4*)qbf_out)[i] = o;
  }
}

// ======== shared 8-step counted-vmcnt GEMM pipeline (round-13 verified template) ========
// BM=128, BN=128, BK=64, 4 waves, 64KB dbuf LDS, vmcnt(8). 8-chunk row-XOR swizzle.
#define PIPE_STAGE(Abase_, Bbase_, kk_, buf_)                                      \
  do {                                                                             \
    _Pragma("unroll")                                                              \
    for (int i_ = 0; i_ < 4; ++i_) {                                               \
      int c_ = tid + i_ * 256;                                                     \
      int row_ = c_ >> 3;                                                          \
      int cc_ = (c_ & 7) ^ (row_ & 7);                                             \
      gload16((Abase_) + (long)row_ * 512 + (kk_) + cc_ * 8,                       \
              (char*)aT[buf_] + (i_ * 256 + w * 64) * 16);                         \
      gload16((Bbase_) + (long)row_ * 512 + (kk_) + cc_ * 8,                       \
              (char*)bT[buf_] + (i_ * 256 + w * 64) * 16);                         \
    }                                                                              \
  } while (0)

#define PIPE_COMPUTE(buf_)                                                         \
  do {                                                                             \
    _Pragma("unroll")                                                              \
    for (int ks_ = 0; ks_ < 2; ++ks_) {                                            \
      bf16x8 af[4], bfr[4];                                                        \
      _Pragma("unroll")                                                            \
      for (int mi_ = 0; mi_ < 4; ++mi_) {                                          \
        int r_ = rm + mi_ * 16 + l15;                                              \
        int p_ = (ks_ * 4 + l4) ^ (r_ & 7);                                        \
        af[mi_] = *(const bf16x8*)((const char*)aT[buf_] + r_ * 128 + p_ * 16);    \
      }                                                                            \
      _Pragma("unroll")                                                            \
      for (int ni_ = 0; ni_ < 4; ++ni_) {                                          \
        int r_ = cn + ni_ * 16 + l15;                                              \
        int p_ = (ks_ * 4 + l4) ^ (r_ & 7);                                        \
        bfr[ni_] = *(const bf16x8*)((const char*)bT[buf_] + r_ * 128 + p_ * 16);   \
      }                                                                            \
      _Pragma("unroll")                                                            \
      for (int mi_ = 0; mi_ < 4; ++mi_)                                            \
        _Pragma("unroll")                                                          \
        for (int ni_ = 0; ni_ < 4; ++ni_)                                          \
          acc[mi_][ni_] = MFMA_BF16(af[mi_], bfr[ni_], acc[mi_][ni_]);             \
    }                                                                              \
  } while (0)

// ---------------- MFMA GEMM: D[r][f] = sum_k A[r][k]*B[f][k] + bias[f] ----------------
// MODE 0: proj (N=1536) -> scatter q(scaled)/k/v bf16, MINW=3.  MODE 1: out-proj, MINW=2.
template <int MODE, int MINW>
__global__ __launch_bounds__(256, MINW) void gemm_kernel(
    const bf16* __restrict__ A, const bf16* __restrict__ B,
    const float* __restrict__ bias,
    bf16* __restrict__ q_out, bf16* __restrict__ k_out, bf16* __restrict__ v_out,
    float* __restrict__ outC) {
  __shared__ __align__(16) bf16 aT[2][128 * 64];
  __shared__ __align__(16) bf16 bT[2][128 * 64];
  const int tid = threadIdx.x;
  const int lane = tid & 63, w = tid >> 6;
  const int l15 = lane & 15, l4 = lane >> 4;
  const long r0 = (long)blockIdx.y * 128;
  const long f0 = (long)blockIdx.x * 128;
  const int rm = (w >> 1) * 64, cn = (w & 1) * 64;
  const bf16* Ab = A + r0 * 512;
  const bf16* Bb = B + f0 * 512;
  f32x4 acc[4][4] = {};

  PIPE_STAGE(Ab, Bb, 0, 0);
  PIPE_STAGE(Ab, Bb, 64, 1);
  asm volatile("s_waitcnt vmcnt(8)" ::: "memory");
  __builtin_amdgcn_s_barrier();
  __builtin_amdgcn_sched_barrier(0);
#pragma unroll
  for (int k = 0; k < 8; ++k) {
    PIPE_COMPUTE(k & 1);
    __builtin_amdgcn_s_barrier();
    __builtin_amdgcn_sched_barrier(0);
    if (k + 2 < 8) PIPE_STAGE(Ab, Bb, (k + 2) * 64, k & 1);
    if (k + 1 < 8) {
      if (k + 2 < 8) asm volatile("s_waitcnt vmcnt(8)" ::: "memory");
      else           asm volatile("s_waitcnt vmcnt(0)" ::: "memory");
      __builtin_amdgcn_s_barrier();
      __builtin_amdgcn_sched_barrier(0);
    }
  }
  // epilogue: C/D layout col=lane&15, row=(lane>>4)*4+reg
#pragma unroll
  for (int mi = 0; mi < 4; ++mi)
#pragma unroll
    for (int ni = 0; ni < 4; ++ni)
#pragma unroll
      for (int r = 0; r < 4; ++r) {
        long row = r0 + rm + mi * 16 + l4 * 4 + r;
        int f = (int)f0 + cn + ni * 16 + l15;
        float val = acc[mi][ni][r] + bias[f];
        if (MODE == 0) {
          int t = (int)(row >> 4), b = (int)(row & 15);
          int which = f >> 9, hh = (f >> 6) & 7, d = f & 63;
          long off = ((long)(b * 8 + hh) * 1024 + t) * 64 + d;
          if (which == 0)      q_out[off] = (bf16)(val * 0.125f);
          else if (which == 1) k_out[off] = (bf16)val;
          else                 v_out[off] = (bf16)val;
        } else {
          outC[row * 512 + f] = val;
        }
      }
}

// ---------------- head-sum GEMM, occupancy-first: per-head acc + packed-bf16 hsum ------
// Wave-private (no s_barrier): B (k) via 8KB/wave LDS dbuf, A (q) fragments direct
// global->reg double-buffered. acc zeroed per head -> minmax reads acc directly (no snap);
// running head-sum packed as 32x u32 (bf16 pairs). Target: <=170 VGPR, 3 waves/SIMD.
__global__ __launch_bounds__(256, 3) void awsum_gemm_kernel(
    const bf16* __restrict__ q_bf, const bf16* __restrict__ k_bf,
    bf16* __restrict__ aw_raw, unsigned* __restrict__ mm) {
  __shared__ __align__(16) char wlds[4][8192];   // per-wave B dbuf: 2 x 4KB
  const int tid = threadIdx.x;
  const int lane = tid & 63, w = tid >> 6;
  const int l15 = lane & 15, l4 = lane >> 4;
  const int bid = blockIdx.x;
  const int xcd = bid & 7, slot = bid >> 3;      // slot 0..127
  const int b = xcd * 2 + (slot >> 6);
  const int rest = slot & 63;                    // 16 t-tiles x 4 s-groups
  const int t0 = (rest >> 2) * 64;
  const int s0w = (rest & 3) * 256 + w * 64;     // per-wave s-origin
  char* lB = wlds[w];

  f32x4 acc[4][4] = {};        // current head partial (zeroed per head)
  unsigned hs[32] = {};        // packed bf16 pairs: idx (mi*4+ni)*2+(r>>1), slot r&1
  float vmin = 1e30f, vmax = -1e30f;

#define BSTAGE(k_, buf_)                                                              \
  do {                                                                                \
    const int hh_ = (k_) >> 1, kh_ = ((k_) & 1) * 32;                                 \
    const bf16* kb_ = k_bf + ((long)(b * 8 + hh_) * 1024 + s0w) * 64 + kh_;           \
    _Pragma("unroll")                                                                 \
    for (int i_ = 0; i_ < 4; ++i_) {                                                  \
      int ci_ = lane + i_ * 64;                                                       \
      int row_ = ci_ >> 2, cc_ = ci_ & 3;                                             \
      int cc2_ = cc_ ^ ((row_ >> 1) & 3);                                             \
      gload16(kb_ + (long)row_ * 64 + cc2_ * 8, lB + (buf_) * 4096 + i_ * 1024);      \
    }                                                                                 \
  } while (0)

#define ALOAD(k_, af_)                                                                \
  do {                                                                                \
    const int hh_ = (k_) >> 1, kh_ = ((k_) & 1) * 32;                                 \
    const bf16* qb_ = q_bf + ((long)(b * 8 + hh_) * 1024 + t0) * 64 + kh_;            \
    _Pragma("unroll")                                                                 \
    for (int mi_ = 0; mi_ < 4; ++mi_)                                                 \
      af_[mi_] = *(const bf16x8*)(qb_ + (long)(mi_ * 16 + l15) * 64 + l4 * 8);        \
  } while (0)

#define WCOMPUTE(buf_, af_)                                                           \
  do {                                                                                \
    bf16x8 bfr[4];                                                                    \
    _Pragma("unroll")                                                                 \
    for (int ni_ = 0; ni_ < 4; ++ni_) {                                               \
      int r_ = ni_ * 16 + l15;                                                        \
      int p_ = l4 ^ ((r_ >> 1) & 3);                                                  \
      bfr[ni_] = *(const bf16x8*)(lB + (buf_) * 4096 + r_ * 64 + p_ * 16);            \
    }                                                                                 \
    _Pragma("unroll")                                                                 \
    for (int mi_ = 0; mi_ < 4; ++mi_)                                                 \
      _Pragma("unroll")                                                               \
      for (int ni_ = 0; ni_ < 4; ++ni_)                                               \
        acc[mi_][ni_] = MFMA_BF16(af_[mi_], bfr[ni_], acc[mi_][ni_]);                 \
  } while (0)

  bf16x8 afA[4], afB[4];
  BSTAGE(0, 0);               // queue: B0(4)
  BSTAGE(1, 1);               // B0,B1
  ALOAD(0, afA);              // B0,B1,A0
#pragma unroll
  for (int k = 0; k < 16; ++k) {
    // A prefetch for step k+1 (alternate named buffers; step k uses afA when k even)
    if (k + 1 < 16) { if (k & 1) ALOAD(k + 1, afA); else ALOAD(k + 1, afB); }
    // wait: B[k] + A[k] done; keep B[k+1] + A[k+1] in flight
    if (k == 0)      asm volatile("s_waitcnt vmcnt(4)" ::: "memory");
    else if (k < 15) asm volatile("s_waitcnt vmcnt(8)" ::: "memory");
    else             asm volatile("s_waitcnt vmcnt(0)" ::: "memory");
    __builtin_amdgcn_sched_barrier(0);
    if (k & 1) WCOMPUTE(k & 1, afB); else WCOMPUTE(k & 1, afA);
    if (k & 1) {  // head (k>>1) complete: minmax on acc, fold into packed hsum, re-zero
#pragma unroll
      for (int mi = 0; mi < 4; ++mi)
#pragma unroll
        for (int ni = 0; ni < 4; ++ni) {
#pragma unroll
          for (int r = 0; r < 4; r += 2) {
            float v0 = acc[mi][ni][r], v1 = acc[mi][ni][r + 1];
            vmin = fminf(vmin, fminf(v0, v1));
            vmax = fmaxf(vmax, fmaxf(v0, v1));
            int hi = (mi * 4 + ni) * 2 + (r >> 1);
            float o0 = __uint_as_float(hs[hi] << 16) + v0;
            float o1 = __uint_as_float(hs[hi] & 0xFFFF0000u) + v1;
            bf16x2 pk; pk[0] = (bf16)o0; pk[1] = (bf16)o1;
            unsigned u; __builtin_memcpy(&u, &pk, 4);
            hs[hi] = u;
          }
          acc[mi][ni] = (f32x4){0.f, 0.f, 0.f, 0.f};
        }
    }
    if (k + 2 < 16) {
      asm volatile("s_waitcnt lgkmcnt(0)" ::: "memory");  // buf's ds_reads done
      __builtin_amdgcn_sched_barrier(0);
      BSTAGE(k + 2, k & 1);                               // safe to overwrite
    }
  }
  // store head-sums from packed hs (bf16)
#pragma unroll
  for (int mi = 0; mi < 4; ++mi)
#pragma unroll
    for (int ni = 0; ni < 4; ++ni)
#pragma unroll
      for (int r = 0; r < 4; ++r) {
        unsigned h = hs[(mi * 4 + ni) * 2 + (r >> 1)];
        unsigned short us = (unsigned short)((r & 1) ? (h >> 16) : (h & 0xFFFFu));
        bf16 val; __builtin_memcpy(&val, &us, 2);
        int t = t0 + mi * 16 + l4 * 4 + r;
        int s = s0w + ni * 16 + l15;
        aw_raw[((long)b * 1024 + t) * 1024 + s] = val;
      }
#pragma unroll
  for (int off = 32; off; off >>= 1) {
    vmin = fminf(vmin, __shfl_xor(vmin, off));
    vmax = fmaxf(vmax, __shfl_xor(vmax, off));
  }
  if (lane == 0) { atomicMin(&mm[0], ordf(vmin)); atomicMax(&mm[1], ordf(vmax)); }
#undef BSTAGE
#undef ALOAD
#undef WCOMPUTE
}

// ---------------- K/V transpose: dst[n][d][s] = src[n][s][d] ----------------
__global__ __launch_bounds__(256) void transpose_kv_kernel(
    const bf16* __restrict__ k_bf, const bf16* __restrict__ v_bf,
    bf16* __restrict__ kT, bf16* __restrict__ vT) {
  const bf16* src = blockIdx.z ? v_bf : k_bf;
  bf16* dst = blockIdx.z ? vT : kT;
  const int n = blockIdx.y;
  const long s0 = (long)blockIdx.x * 64;
  __shared__ __align__(16) bf16 tile[64][72];
  const int tid = threadIdx.x;
  const int row = tid >> 3, cc = tid & 7;
#pragma unroll
  for (int it = 0; it < 2; ++it) {
    int r = row + it * 32;
    bf16x8 vv = *(const bf16x8*)(src + ((long)n * 1024 + s0 + r) * 64 + cc * 8);
    *(bf16x8*)&tile[r][cc * 8] = vv;
  }
  __syncthreads();
#pragma unroll
  for (int it = 0; it < 2; ++it) {
    int d = row + it * 32;
    bf16x8 ov;
#pragma unroll
    for (int j = 0; j < 8; ++j) ov[j] = tile[cc * 8 + j][d];
    *(bf16x8*)(dst + ((long)n * 64 + d) * 1024 + s0 + cc * 8) = ov;
  }
}

// ---------------- merged small reductions: vcolsum (blocks 0..127) + bias_col (128..639) ----
__global__ __launch_bounds__(256) void reduce_small_kernel(
    const bf16* __restrict__ vT, const float* __restrict__ bias_v,
    float* __restrict__ vcs, const bf16* __restrict__ q_bf,
    const float* __restrict__ bias_k, float* __restrict__ aw_last,
    unsigned* __restrict__ mm) {
  if (blockIdx.x < 128) {
    const int n = blockIdx.x, h = n & 7;
    const int d = threadIdx.x >> 2, q = threadIdx.x & 3;
    float acc = 0.f;
    const bf16* row = vT + (long)n * 65536 + (long)d * 1024 + q * 256;
#pragma unroll 4
    for (int j = 0; j < 32; ++j) {
      bf16x8 v = *(const bf16x8*)(row + j * 8);
#pragma unroll
      for (int e = 0; e < 8; ++e) acc += (float)v[e];
    }
    __shared__ float red[256];
    red[threadIdx.x] = acc;
    __syncthreads();
    if (q == 0)
      vcs[n * 64 + d] = red[d * 4] + red[d * 4 + 1] + red[d * 4 + 2] + red[d * 4 + 3] +
                        bias_v[h * 64 + d];
  } else {
    const int lin = blockIdx.x - 128;
    const int bx = lin & 3, n = lin >> 2, h = n & 7;
    const int t = bx * 256 + threadIdx.x;
    float acc = 0.f;
    const bf16* qrow = q_bf + ((long)n * 1024 + t) * 64;
#pragma unroll
    for (int j = 0; j < 8; ++j) {
      bf16x8 qv = *(const bf16x8*)(qrow + j * 8);
#pragma unroll
      for (int e = 0; e < 8; ++e) acc += (float)qv[e] * bias_k[h * 64 + j * 8 + e];
    }
    aw_last[(long)n * 1024 + t] = acc;
    float vmin = acc, vmax = acc;
#pragma unroll
    for (int off = 32; off; off >>= 1) {
      vmin = fminf(vmin, __shfl_xor(vmin, off));
      vmax = fmaxf(vmax, __shfl_xor(vmax, off));
    }
    if ((threadIdx.x & 63) == 0) { atomicMin(&mm[0], ordf(vmin)); atomicMax(&mm[1], ordf(vmax)); }
  }
}

// ---------------- K^T V: ktvT[n][d'][d] = sum_{s<1024} k[n,s,d]*v[n,s,d'] (bf16 out) ----
__global__ __launch_bounds__(256) void ktv_kernel(const bf16* __restrict__ kT,
                                                  const bf16* __restrict__ vT,
                                                  bf16* __restrict__ ktvT) {
  const int n = blockIdx.x;
  const int tid = threadIdx.x;
  const int lane = tid & 63, w = tid >> 6;
  const int l15 = lane & 15, l4 = lane >> 4;
  const int wr = w >> 1, wc = w & 1;
  f32x4 acc[2][2] = {};
  const bf16* kbase = kT + (long)n * 65536;   // [d][s]
  const bf16* vbase = vT + (long)n * 65536;   // [d'][s]
  for (int s0 = 0; s0 < 1024; s0 += 32) {
    bf16x8 af[2], bfr[2];
#pragma unroll
    for (int mi = 0; mi < 2; ++mi)
      af[mi] = *(const bf16x8*)(kbase + (long)(wr * 32 + mi * 16 + l15) * 1024 + s0 + l4 * 8);
#pragma unroll
    for (int ni = 0; ni < 2; ++ni)
      bfr[ni] = *(const bf16x8*)(vbase + (long)(wc * 32 + ni * 16 + l15) * 1024 + s0 + l4 * 8);
#pragma unroll
    for (int mi = 0; mi < 2; ++mi)
#pragma unroll
      for (int ni = 0; ni < 2; ++ni)
        acc[mi][ni] = MFMA_BF16(af[mi], bfr[ni], acc[mi][ni]);
  }
#pragma unroll
  for (int mi = 0; mi < 2; ++mi)
#pragma unroll
    for (int ni = 0; ni < 2; ++ni)
#pragma unroll
      for (int r = 0; r < 4; ++r) {
        int d = wr * 32 + mi * 16 + l4 * 4 + r;
        int dp = wc * 32 + ni * 16 + l15;
        ktvT[(long)n * 4096 + dp * 64 + d] = (bf16)acc[mi][ni][r];
      }
}

// ---------------- fused Q*(K^T V) + affine -> A2 bf16 [r=(t,b)][e'=(h,d')] ----------
__global__ __launch_bounds__(256) void qattn_kernel(
    const bf16* __restrict__ q_bf, const bf16* __restrict__ ktvT,
    const float* __restrict__ aw_last, const float* __restrict__ vcs,
    const float* __restrict__ bias_v, const unsigned* __restrict__ mm,
    bf16* __restrict__ A2) {
  const int tid = threadIdx.x;
  const int lane = tid & 63, w = tid >> 6;
  const int l15 = lane & 15, l4 = lane >> 4;
  const int t0 = blockIdx.x * 64;
  const int h = blockIdx.y * 4 + w;
  const int b = blockIdx.z;
  const long n = (long)b * 8 + h;
  f32x4 acc[4][4] = {};
  const bf16* qbase = q_bf + (n * 1024 + t0) * 64;
  const bf16* kbase = ktvT + (long)n * 4096;   // [d'][d]
#pragma unroll
  for (int kk = 0; kk < 64; kk += 32) {
    bf16x8 af[4], bfr[4];
#pragma unroll
    for (int mi = 0; mi < 4; ++mi)
      af[mi] = *(const bf16x8*)(qbase + (mi * 16 + l15) * 64 + kk + l4 * 8);
#pragma unroll
    for (int ni = 0; ni < 4; ++ni)
      bfr[ni] = *(const bf16x8*)(kbase + (ni * 16 + l15) * 64 + kk + l4 * 8);
#pragma unroll
    for (int mi = 0; mi < 4; ++mi)
#pragma unroll
      for (int ni = 0; ni < 4; ++ni)
        acc[mi][ni] = MFMA_BF16(af[mi], bfr[ni], acc[mi][ni]);
  }
  float mn = deordf(mm[0]), mx = deordf(mm[1]);
  float a = 1.f / (mx - mn), c = -mn * a;
#pragma unroll
  for (int mi = 0; mi < 4; ++mi)
#pragma unroll
    for (int r = 0; r < 4; ++r) {
      int t = t0 + mi * 16 + l4 * 4 + r;
      float alast = a * aw_last[n * 1024 + t];
#pragma unroll
      for (int ni = 0; ni < 4; ++ni) {
        int dp = ni * 16 + l15;
        float val = a * acc[mi][ni][r] + alast * bias_v[h * 64 + dp] + c * vcs[n * 64 + dp];
        A2[((long)t * 16 + b) * 512 + h * 64 + dp] = (bf16)val;
      }
    }
}

// ---------------- final aw_avg: affine(raw bf16) + s=1024 column ----------------
__global__ __launch_bounds__(256) void rescale_kernel(const bf16* __restrict__ aw_raw,
                                                      float* __restrict__ aw_out,
                                                      const float* __restrict__ aw_last,
                                                      const unsigned* __restrict__ mm) {
  long idx = (long)blockIdx.x * 256 + threadIdx.x;   // 0..16793599
  float mn = deordf(mm[0]), mx = deordf(mm[1]);
  float a = 1.f / (mx - mn), c = -mn * a;
  int s = (int)(idx % 1025);
  long bt = idx / 1025;
  float v;
  if (s < 1024) {
    v = (float)aw_raw[bt * 1024 + s];
  } else {
    int b = (int)(bt >> 10), t = (int)(bt & 1023);
    v = 0.f;
#pragma unroll
    for (int h = 0; h < 8; ++h) v += aw_last[(long)(b * 8 + h) * 1024 + t];
  }
  aw_out[idx] = fmaf(a, v * 0.125f, c);
}

// ---------------- launcher ----------------
extern "C" void kernel_launch(void* const* d_in, const int* in_sizes, int n_in,
                              void* d_out, int out_size, void* d_ws, size_t ws_size,
                              hipStream_t stream) {
  const float* query  = (const float*)d_in[0];
  const float* i_proj = (const float*)d_in[1];
  const float* in_w   = (const float*)d_in[2];
  const float* in_b   = (const float*)d_in[3];
  const float* out_w  = (const float*)d_in[4];
  const float* out_b  = (const float*)d_in[5];
  const float* bias_k = (const float*)d_in[6];
  const float* bias_v = (const float*)d_in[7];
  float* out = (float*)d_out;

  char* ws = (char*)d_ws;
  bf16* qbf_in = (bf16*)(ws + WS_QBF_IN);
  bf16* w_bf   = (bf16*)(ws + WS_WBF);
  bf16* outwbf = (bf16*)(ws + WS_OUTWBF);
  bf16* q_bf   = (bf16*)(ws + WS_Q);
  bf16* k_bf   = (bf16*)(ws + WS_K);
  bf16* v_bf   = (bf16*)(ws + WS_V);
  bf16* vT     = (bf16*)(ws + WS_VT);
  bf16* kT     = (bf16*)(ws + WS_KT);
  bf16* ktvT   = (bf16*)(ws + WS_KTV);
  bf16* aw_raw = (bf16*)(ws + WS_V);    // reuses v_bf+vT (33.5MB) after ktv
  float* aw_last = (float*)(ws + WS_AWLAST);
  float* vcs     = (float*)(ws + WS_VCS);
  unsigned* mm   = (unsigned*)(ws + WS_MM);
  bf16* A2 = qbf_in;  // reuse: qbf_in dead after proj GEMM

  float* out_attn  = out;                       // (1024,16,512)
  float* out_awavg = out + 8388608L;            // (16,1024,1025)
  float* out_wret  = out + 25182208L;           // (3,512,512)

  prep_all_kernel<<<4096, 256, 0, stream>>>(query, qbf_in, in_w, i_proj, out_w,
                                            w_bf, outwbf, out_wret, mm);
  gemm_kernel<0, 3><<<dim3(12, 128), 256, 0, stream>>>(qbf_in, w_bf, in_b,
                                                       q_bf, k_bf, v_bf, nullptr);
  transpose_kv_kernel<<<dim3(16, 128, 2), 256, 0, stream>>>(k_bf, v_bf, kT, vT);
  reduce_small_kernel<<<640, 256, 0, stream>>>(vT, bias_v, vcs, q_bf, bias_k, aw_last, mm);
  ktv_kernel<<<128, 256, 0, stream>>>(kT, vT, ktvT);           // frees vT/v_bf region
  awsum_gemm_kernel<<<1024, 256, 0, stream>>>(q_bf, k_bf, aw_raw, mm);
  rescale_kernel<<<65600, 256, 0, stream>>>(aw_raw, out_awavg, aw_last, mm);
  qattn_kernel<<<dim3(16, 2, 16), 256, 0, stream>>>(q_bf, ktvT, aw_last, vcs, bias_v, mm, A2);
  gemm_kernel<1, 2><<<dim3(4, 128), 256, 0, stream>>>(A2, outwbf, out_b,
                                                      nullptr, nullptr, nullptr, out_attn);
}

// Round 20
// 299.676 us; speedup vs baseline: 1.2427x; 1.2427x over previous
//
#include <hip/hip_runtime.h>
#include <hip/hip_bf16.h>
#include <stdint.h>

// Problem constants: E=512, H=8, hd=64, T=1024, B=16, N=B*H=128, S=1025
typedef __bf16 bf16;
typedef __bf16 bf16x8 __attribute__((ext_vector_type(8)));
typedef __bf16 bf16x4 __attribute__((ext_vector_type(4)));
typedef float  f32x4  __attribute__((ext_vector_type(4)));

#define MFMA_BF16(a,b,c) __builtin_amdgcn_mfma_f32_16x16x32_bf16((a),(b),(c),0,0,0)

// ---- workspace byte offsets (total ~104.4 MB) ----
#define WS_QBF_IN  0L            // 16777216  query bf16 [r=(t,b)][e]   (reused as A2 later)
#define WS_WBF     16777216L     // 1572864   mutated in_proj_weight bf16 [f][e]
#define WS_OUTWBF  18350080L     // 524288    out_w bf16 [e][e']
#define WS_Q       18874368L     // 16777216  q*0.125 bf16 [n][t][d]
#define WS_K       35651584L     // 16777216  k bf16 [n][s<1024][d]
#define WS_V       52428800L     // 16777216  v bf16 [n][s<1024][d]; + vT = 33.5MB contig,
                                 //           reused as aw_raw bf16 [b][t][s<1024] after ktv
#define WS_VT      69206016L     // 16777216  v^T bf16 [n][d][s<1024]
#define WS_AWLAST  85983232L     // 524288    fp32 aw[:, :, 1024] as [n][t]
#define WS_VCS     86507520L     // 32768     fp32 col-sum of v (incl bias row) [n][d]
#define WS_MM      86540288L     // 8         {min,max} ordered-uint
#define WS_KT      86540544L     // 16777216  k^T bf16 [n][d][s<1024]
#define WS_KTV     103317760L    // 1048576   (K^T V)^T bf16 [n][d'][d]

__device__ __forceinline__ void gload16(const void* g, void* l) {
  __builtin_amdgcn_global_load_lds((const __attribute__((address_space(1))) uint32_t*)g,
                                   (__attribute__((address_space(3))) uint32_t*)l, 16, 0, 0);
}
__device__ __forceinline__ unsigned ordf(float x) {
  unsigned b = __float_as_uint(x);
  return (b & 0x80000000u) ? ~b : (b | 0x80000000u);
}
__device__ __forceinline__ float deordf(unsigned u) {
  unsigned b = (u & 0x80000000u) ? (u ^ 0x80000000u) : ~u;
  return __uint_as_float(b);
}

// ---------------- merged prep: query cvt + weight mutation/convert + w_ret ----------------
__global__ __launch_bounds__(256) void prep_all_kernel(
    const float* __restrict__ query, bf16* __restrict__ qbf_out,
    const float* __restrict__ in_w, const float* __restrict__ i_proj,
    const float* __restrict__ out_w, bf16* __restrict__ w_bf,
    bf16* __restrict__ outw_bf, float* __restrict__ w_ret,
    unsigned* __restrict__ mm) {
  long idx = (long)blockIdx.x * 256 + threadIdx.x;   // grid 4096 -> 0..1048575
  if (idx == 0) { mm[0] = 0xFFFFFFFFu; mm[1] = 0u; } // min-slot, max-slot
  if (idx < 786432L) {
    int f = (int)(idx >> 9), e = (int)(idx & 511);
    float val = (e % 3 == 0) ? i_proj[f] : in_w[idx];
    w_bf[idx] = (bf16)val;
    w_ret[(long)(f >> 9) * 262144 + (long)e * 512 + (f & 511)] = val;   // w_ret[m][e][f%512]
  } else if (idx < 1048576L) {
    long j = idx - 786432L;
    outw_bf[j] = (bf16)out_w[j];
  }
  // query cvt: 2097152 float4s, 2 per thread
#pragma unroll
  for (int it = 0; it < 2; ++it) {
    long i = idx + (long)it * 1048576L;
    float4 v = ((const float4*)query)[i];
    bf16x4 o; o[0] = (bf16)v.x; o[1] = (bf16)v.y; o[2] = (bf16)v.z; o[3] = (bf16)v.w;
    ((bf16x4*)qbf_out)[i] = o;
  }
}

// ======== shared 8-step counted-vmcnt GEMM pipeline (round-13 verified template) ========
// BM=128, BN=128, BK=64, 4 waves, 64KB dbuf LDS, vmcnt(8). 8-chunk row-XOR swizzle.
#define PIPE_STAGE(Abase_, Bbase_, kk_, buf_)                                      \
  do {                                                                             \
    _Pragma("unroll")                                                              \
    for (int i_ = 0; i_ < 4; ++i_) {                                               \
      int c_ = tid + i_ * 256;                                                     \
      int row_ = c_ >> 3;                                                          \
      int cc_ = (c_ & 7) ^ (row_ & 7);                                             \
      gload16((Abase_) + (long)row_ * 512 + (kk_) + cc_ * 8,                       \
              (char*)aT[buf_] + (i_ * 256 + w * 64) * 16);                         \
      gload16((Bbase_) + (long)row_ * 512 + (kk_) + cc_ * 8,                       \
              (char*)bT[buf_] + (i_ * 256 + w * 64) * 16);                         \
    }                                                                              \
  } while (0)

#define PIPE_COMPUTE(buf_)                                                         \
  do {                                                                             \
    _Pragma("unroll")                                                              \
    for (int ks_ = 0; ks_ < 2; ++ks_) {                                            \
      bf16x8 af[4], bfr[4];                                                        \
      _Pragma("unroll")                                                            \
      for (int mi_ = 0; mi_ < 4; ++mi_) {                                          \
        int r_ = rm + mi_ * 16 + l15;                                              \
        int p_ = (ks_ * 4 + l4) ^ (r_ & 7);                                        \
        af[mi_] = *(const bf16x8*)((const char*)aT[buf_] + r_ * 128 + p_ * 16);    \
      }                                                                            \
      _Pragma("unroll")                                                            \
      for (int ni_ = 0; ni_ < 4; ++ni_) {                                          \
        int r_ = cn + ni_ * 16 + l15;                                              \
        int p_ = (ks_ * 4 + l4) ^ (r_ & 7);                                        \
        bfr[ni_] = *(const bf16x8*)((const char*)bT[buf_] + r_ * 128 + p_ * 16);   \
      }                                                                            \
      _Pragma("unroll")                                                            \
      for (int mi_ = 0; mi_ < 4; ++mi_)                                            \
        _Pragma("unroll")                                                          \
        for (int ni_ = 0; ni_ < 4; ++ni_)                                          \
          acc[mi_][ni_] = MFMA_BF16(af[mi_], bfr[ni_], acc[mi_][ni_]);             \
    }                                                                              \
  } while (0)

// ---------------- MFMA GEMM: D[r][f] = sum_k A[r][k]*B[f][k] + bias[f] ----------------
// MODE 0: proj (N=1536) -> scatter q(scaled)/k/v bf16, MINW=3 (1536 blocks -> 2 rounds).
// MODE 1: out-proj (N=512) -> fp32 rows, MINW=2 (512 blocks = 1 round at 2/CU).
template <int MODE, int MINW>
__global__ __launch_bounds__(256, MINW) void gemm_kernel(
    const bf16* __restrict__ A, const bf16* __restrict__ B,
    const float* __restrict__ bias,
    bf16* __restrict__ q_out, bf16* __restrict__ k_out, bf16* __restrict__ v_out,
    float* __restrict__ outC) {
  __shared__ __align__(16) bf16 aT[2][128 * 64];
  __shared__ __align__(16) bf16 bT[2][128 * 64];
  const int tid = threadIdx.x;
  const int lane = tid & 63, w = tid >> 6;
  const int l15 = lane & 15, l4 = lane >> 4;
  const long r0 = (long)blockIdx.y * 128;
  const long f0 = (long)blockIdx.x * 128;
  const int rm = (w >> 1) * 64, cn = (w & 1) * 64;
  const bf16* Ab = A + r0 * 512;
  const bf16* Bb = B + f0 * 512;
  f32x4 acc[4][4] = {};

  PIPE_STAGE(Ab, Bb, 0, 0);
  PIPE_STAGE(Ab, Bb, 64, 1);
  asm volatile("s_waitcnt vmcnt(8)" ::: "memory");
  __builtin_amdgcn_s_barrier();
  __builtin_amdgcn_sched_barrier(0);
#pragma unroll
  for (int k = 0; k < 8; ++k) {
    PIPE_COMPUTE(k & 1);
    __builtin_amdgcn_s_barrier();
    __builtin_amdgcn_sched_barrier(0);
    if (k + 2 < 8) PIPE_STAGE(Ab, Bb, (k + 2) * 64, k & 1);
    if (k + 1 < 8) {
      if (k + 2 < 8) asm volatile("s_waitcnt vmcnt(8)" ::: "memory");
      else           asm volatile("s_waitcnt vmcnt(0)" ::: "memory");
      __builtin_amdgcn_s_barrier();
      __builtin_amdgcn_sched_barrier(0);
    }
  }
  // epilogue: C/D layout col=lane&15, row=(lane>>4)*4+reg
#pragma unroll
  for (int mi = 0; mi < 4; ++mi)
#pragma unroll
    for (int ni = 0; ni < 4; ++ni)
#pragma unroll
      for (int r = 0; r < 4; ++r) {
        long row = r0 + rm + mi * 16 + l4 * 4 + r;
        int f = (int)f0 + cn + ni * 16 + l15;
        float val = acc[mi][ni][r] + bias[f];
        if (MODE == 0) {
          int t = (int)(row >> 4), b = (int)(row & 15);
          int which = f >> 9, hh = (f >> 6) & 7, d = f & 63;
          long off = ((long)(b * 8 + hh) * 1024 + t) * 64 + d;
          if (which == 0)      q_out[off] = (bf16)(val * 0.125f);
          else if (which == 1) k_out[off] = (bf16)val;
          else                 v_out[off] = (bf16)val;
        } else {
          outC[row * 512 + f] = val;
        }
      }
}

// ---------------- head-sum GEMM + fused per-head min/max, BARRIER-FREE ----------------
// Each wave owns a 64x64 output tile + private 16KB LDS slice (A/B 64x32 dbuf).
// 16 steps of BK=32; head boundary every 2 steps -> delta/snap min-max. (measured ~112us,
// the floor across 6 structural variants; acc+snap=128 AGPRs cap occupancy at 2 waves/SIMD)
__global__ __launch_bounds__(256, 2) void awsum_gemm_kernel(
    const bf16* __restrict__ q_bf, const bf16* __restrict__ k_bf,
    bf16* __restrict__ aw_raw, unsigned* __restrict__ mm) {
  __shared__ __align__(16) char wlds[4][16384];   // per-wave: A dbuf 2x4KB @0, B dbuf @8192
  const int tid = threadIdx.x;
  const int lane = tid & 63, w = tid >> 6;
  const int l15 = lane & 15, l4 = lane >> 4;
  const int bid = blockIdx.x;
  const int xcd = bid & 7, slot = bid >> 3;      // slot 0..127
  const int b = xcd * 2 + (slot >> 6);
  const int rest = slot & 63;                    // 16 t-tiles x 4 s-groups
  const int t0 = (rest >> 2) * 64;
  const int s0w = (rest & 3) * 256 + w * 64;     // per-wave s-origin
  char* lA = wlds[w];
  char* lB = wlds[w] + 8192;

  f32x4 acc[4][4] = {};
  f32x4 snap[4][4] = {};
  float vmin = 1e30f, vmax = -1e30f;

#define WAVE_STAGE(k_, buf_)                                                          \
  do {                                                                                \
    const int hh_ = (k_) >> 1, kh_ = ((k_) & 1) * 32;                                 \
    const bf16* qb_ = q_bf + ((long)(b * 8 + hh_) * 1024 + t0) * 64 + kh_;            \
    const bf16* kb_ = k_bf + ((long)(b * 8 + hh_) * 1024 + s0w) * 64 + kh_;           \
    _Pragma("unroll")                                                                 \
    for (int i_ = 0; i_ < 4; ++i_) {                                                  \
      int ci_ = lane + i_ * 64;                                                       \
      int row_ = ci_ >> 2, cc_ = ci_ & 3;                                             \
      int cc2_ = cc_ ^ ((row_ >> 1) & 3);                                             \
      gload16(qb_ + (long)row_ * 64 + cc2_ * 8, lA + (buf_) * 4096 + i_ * 1024);      \
      gload16(kb_ + (long)row_ * 64 + cc2_ * 8, lB + (buf_) * 4096 + i_ * 1024);      \
    }                                                                                 \
  } while (0)

#define WAVE_COMPUTE(buf_)                                                            \
  do {                                                                                \
    bf16x8 af[4], bfr[4];                                                             \
    _Pragma("unroll")                                                                 \
    for (int mi_ = 0; mi_ < 4; ++mi_) {                                               \
      int r_ = mi_ * 16 + l15;                                                        \
      int p_ = l4 ^ ((r_ >> 1) & 3);                                                  \
      af[mi_] = *(const bf16x8*)(lA + (buf_) * 4096 + r_ * 64 + p_ * 16);             \
    }                                                                                 \
    _Pragma("unroll")                                                                 \
    for (int ni_ = 0; ni_ < 4; ++ni_) {                                               \
      int r_ = ni_ * 16 + l15;                                                        \
      int p_ = l4 ^ ((r_ >> 1) & 3);                                                  \
      bfr[ni_] = *(const bf16x8*)(lB + (buf_) * 4096 + r_ * 64 + p_ * 16);            \
    }                                                                                 \
    _Pragma("unroll")                                                                 \
    for (int mi_ = 0; mi_ < 4; ++mi_)                                                 \
      _Pragma("unroll")                                                               \
      for (int ni_ = 0; ni_ < 4; ++ni_)                                               \
        acc[mi_][ni_] = MFMA_BF16(af[mi_], bfr[ni_], acc[mi_][ni_]);                  \
  } while (0)

  WAVE_STAGE(0, 0);
  WAVE_STAGE(1, 1);
#pragma unroll
  for (int k = 0; k < 16; ++k) {
    if (k < 15) asm volatile("s_waitcnt vmcnt(8)" ::: "memory");   // step k's 8 loads done
    else        asm volatile("s_waitcnt vmcnt(0)" ::: "memory");
    __builtin_amdgcn_sched_barrier(0);
    WAVE_COMPUTE(k & 1);
    if (k & 1) {  // head (k>>1) complete: flush
#pragma unroll
      for (int mi = 0; mi < 4; ++mi)
#pragma unroll
        for (int ni = 0; ni < 4; ++ni) {
          f32x4 d = acc[mi][ni] - snap[mi][ni];
#pragma unroll
          for (int r = 0; r < 4; ++r) {
            vmin = fminf(vmin, d[r]);
            vmax = fmaxf(vmax, d[r]);
          }
          snap[mi][ni] = acc[mi][ni];
        }
    }
    if (k + 2 < 16) {
      asm volatile("s_waitcnt lgkmcnt(0)" ::: "memory");  // this step's ds_reads done
      __builtin_amdgcn_sched_barrier(0);
      WAVE_STAGE(k + 2, k & 1);
    }
  }
#pragma unroll
  for (int mi = 0; mi < 4; ++mi)
#pragma unroll
    for (int ni = 0; ni < 4; ++ni)
#pragma unroll
      for (int r = 0; r < 4; ++r) {
        int t = t0 + mi * 16 + l4 * 4 + r;
        int s = s0w + ni * 16 + l15;
        aw_raw[((long)b * 1024 + t) * 1024 + s] = (bf16)acc[mi][ni][r];
      }
#pragma unroll
  for (int off = 32; off; off >>= 1) {
    vmin = fminf(vmin, __shfl_xor(vmin, off));
    vmax = fmaxf(vmax, __shfl_xor(vmax, off));
  }
  if (lane == 0) { atomicMin(&mm[0], ordf(vmin)); atomicMax(&mm[1], ordf(vmax)); }
#undef WAVE_STAGE
#undef WAVE_COMPUTE
}

// ---------------- K/V transpose: dst[n][d][s] = src[n][s][d] ----------------
__global__ __launch_bounds__(256) void transpose_kv_kernel(
    const bf16* __restrict__ k_bf, const bf16* __restrict__ v_bf,
    bf16* __restrict__ kT, bf16* __restrict__ vT) {
  const bf16* src = blockIdx.z ? v_bf : k_bf;
  bf16* dst = blockIdx.z ? vT : kT;
  const int n = blockIdx.y;
  const long s0 = (long)blockIdx.x * 64;
  __shared__ __align__(16) bf16 tile[64][72];
  const int tid = threadIdx.x;
  const int row = tid >> 3, cc = tid & 7;
#pragma unroll
  for (int it = 0; it < 2; ++it) {
    int r = row + it * 32;
    bf16x8 vv = *(const bf16x8*)(src + ((long)n * 1024 + s0 + r) * 64 + cc * 8);
    *(bf16x8*)&tile[r][cc * 8] = vv;
  }
  __syncthreads();
#pragma unroll
  for (int it = 0; it < 2; ++it) {
    int d = row + it * 32;
    bf16x8 ov;
#pragma unroll
    for (int j = 0; j < 8; ++j) ov[j] = tile[cc * 8 + j][d];
    *(bf16x8*)(dst + ((long)n * 64 + d) * 1024 + s0 + cc * 8) = ov;
  }
}

// ---------------- merged small reductions: vcolsum (blocks 0..127) + bias_col (128..639) ----
__global__ __launch_bounds__(256) void reduce_small_kernel(
    const bf16* __restrict__ vT, const float* __restrict__ bias_v,
    float* __restrict__ vcs, const bf16* __restrict__ q_bf,
    const float* __restrict__ bias_k, float* __restrict__ aw_last,
    unsigned* __restrict__ mm) {
  if (blockIdx.x < 128) {
    // v column sum from vT rows (coalesced) + bias_v row
    const int n = blockIdx.x, h = n & 7;
    const int d = threadIdx.x >> 2, q = threadIdx.x & 3;
    float acc = 0.f;
    const bf16* row = vT + (long)n * 65536 + (long)d * 1024 + q * 256;
#pragma unroll 4
    for (int j = 0; j < 32; ++j) {
      bf16x8 v = *(const bf16x8*)(row + j * 8);
#pragma unroll
      for (int e = 0; e < 8; ++e) acc += (float)v[e];
    }
    __shared__ float red[256];
    red[threadIdx.x] = acc;
    __syncthreads();
    if (q == 0)
      vcs[n * 64 + d] = red[d * 4] + red[d * 4 + 1] + red[d * 4 + 2] + red[d * 4 + 3] +
                        bias_v[h * 64 + d];
  } else {
    // bias column s=1024: aw_last[n][t] = q[n][t][:] . bias_k[h]
    const int lin = blockIdx.x - 128;
    const int bx = lin & 3, n = lin >> 2, h = n & 7;
    const int t = bx * 256 + threadIdx.x;
    float acc = 0.f;
    const bf16* qrow = q_bf + ((long)n * 1024 + t) * 64;
#pragma unroll
    for (int j = 0; j < 8; ++j) {
      bf16x8 qv = *(const bf16x8*)(qrow + j * 8);
#pragma unroll
      for (int e = 0; e < 8; ++e) acc += (float)qv[e] * bias_k[h * 64 + j * 8 + e];
    }
    aw_last[(long)n * 1024 + t] = acc;
    float vmin = acc, vmax = acc;
#pragma unroll
    for (int off = 32; off; off >>= 1) {
      vmin = fminf(vmin, __shfl_xor(vmin, off));
      vmax = fmaxf(vmax, __shfl_xor(vmax, off));
    }
    if ((threadIdx.x & 63) == 0) { atomicMin(&mm[0], ordf(vmin)); atomicMax(&mm[1], ordf(vmax)); }
  }
}

// ---------------- K^T V: ktvT[n][d'][d] = sum_{s<1024} k[n,s,d]*v[n,s,d'] (bf16 out) ----
__global__ __launch_bounds__(256) void ktv_kernel(const bf16* __restrict__ kT,
                                                  const bf16* __restrict__ vT,
                                                  bf16* __restrict__ ktvT) {
  const int n = blockIdx.x;
  const int tid = threadIdx.x;
  const int lane = tid & 63, w = tid >> 6;
  const int l15 = lane & 15, l4 = lane >> 4;
  const int wr = w >> 1, wc = w & 1;
  f32x4 acc[2][2] = {};
  const bf16* kbase = kT + (long)n * 65536;   // [d][s]
  const bf16* vbase = vT + (long)n * 65536;   // [d'][s]
  for (int s0 = 0; s0 < 1024; s0 += 32) {
    bf16x8 af[2], bfr[2];
#pragma unroll
    for (int mi = 0; mi < 2; ++mi)
      af[mi] = *(const bf16x8*)(kbase + (long)(wr * 32 + mi * 16 + l15) * 1024 + s0 + l4 * 8);
#pragma unroll
    for (int ni = 0; ni < 2; ++ni)
      bfr[ni] = *(const bf16x8*)(vbase + (long)(wc * 32 + ni * 16 + l15) * 1024 + s0 + l4 * 8);
#pragma unroll
    for (int mi = 0; mi < 2; ++mi)
#pragma unroll
      for (int ni = 0; ni < 2; ++ni)
        acc[mi][ni] = MFMA_BF16(af[mi], bfr[ni], acc[mi][ni]);
  }
#pragma unroll
  for (int mi = 0; mi < 2; ++mi)
#pragma unroll
    for (int ni = 0; ni < 2; ++ni)
#pragma unroll
      for (int r = 0; r < 4; ++r) {
        int d = wr * 32 + mi * 16 + l4 * 4 + r;
        int dp = wc * 32 + ni * 16 + l15;
        ktvT[(long)n * 4096 + dp * 64 + d] = (bf16)acc[mi][ni][r];
      }
}

// ---------------- fused Q*(K^T V) + affine -> A2 bf16 [r=(t,b)][e'=(h,d')] ----------
__global__ __launch_bounds__(256) void qattn_kernel(
    const bf16* __restrict__ q_bf, const bf16* __restrict__ ktvT,
    const float* __restrict__ aw_last, const float* __restrict__ vcs,
    const float* __restrict__ bias_v, const unsigned* __restrict__ mm,
    bf16* __restrict__ A2) {
  const int tid = threadIdx.x;
  const int lane = tid & 63, w = tid >> 6;
  const int l15 = lane & 15, l4 = lane >> 4;
  const int t0 = blockIdx.x * 64;
  const int h = blockIdx.y * 4 + w;
  const int b = blockIdx.z;
  const long n = (long)b * 8 + h;
  f32x4 acc[4][4] = {};
  const bf16* qbase = q_bf + (n * 1024 + t0) * 64;
  const bf16* kbase = ktvT + (long)n * 4096;   // [d'][d]
#pragma unroll
  for (int kk = 0; kk < 64; kk += 32) {
    bf16x8 af[4], bfr[4];
#pragma unroll
    for (int mi = 0; mi < 4; ++mi)
      af[mi] = *(const bf16x8*)(qbase + (mi * 16 + l15) * 64 + kk + l4 * 8);
#pragma unroll
    for (int ni = 0; ni < 4; ++ni)
      bfr[ni] = *(const bf16x8*)(kbase + (ni * 16 + l15) * 64 + kk + l4 * 8);
#pragma unroll
    for (int mi = 0; mi < 4; ++mi)
#pragma unroll
      for (int ni = 0; ni < 4; ++ni)
        acc[mi][ni] = MFMA_BF16(af[mi], bfr[ni], acc[mi][ni]);
  }
  float mn = deordf(mm[0]), mx = deordf(mm[1]);
  float a = 1.f / (mx - mn), c = -mn * a;
#pragma unroll
  for (int mi = 0; mi < 4; ++mi)
#pragma unroll
    for (int r = 0; r < 4; ++r) {
      int t = t0 + mi * 16 + l4 * 4 + r;
      float alast = a * aw_last[n * 1024 + t];
#pragma unroll
      for (int ni = 0; ni < 4; ++ni) {
        int dp = ni * 16 + l15;
        float val = a * acc[mi][ni][r] + alast * bias_v[h * 64 + dp] + c * vcs[n * 64 + dp];
        A2[((long)t * 16 + b) * 512 + h * 64 + dp] = (bf16)val;
      }
    }
}

// ---------------- final aw_avg: affine(raw bf16) + s=1024 column ----------------
__global__ __launch_bounds__(256) void rescale_kernel(const bf16* __restrict__ aw_raw,
                                                      float* __restrict__ aw_out,
                                                      const float* __restrict__ aw_last,
                                                      const unsigned* __restrict__ mm) {
  long idx = (long)blockIdx.x * 256 + threadIdx.x;   // 0..16793599
  float mn = deordf(mm[0]), mx = deordf(mm[1]);
  float a = 1.f / (mx - mn), c = -mn * a;
  int s = (int)(idx % 1025);
  long bt = idx / 1025;
  float v;
  if (s < 1024) {
    v = (float)aw_raw[bt * 1024 + s];
  } else {
    int b = (int)(bt >> 10), t = (int)(bt & 1023);
    v = 0.f;
#pragma unroll
    for (int h = 0; h < 8; ++h) v += aw_last[(long)(b * 8 + h) * 1024 + t];
  }
  aw_out[idx] = fmaf(a, v * 0.125f, c);
}

// ---------------- launcher ----------------
extern "C" void kernel_launch(void* const* d_in, const int* in_sizes, int n_in,
                              void* d_out, int out_size, void* d_ws, size_t ws_size,
                              hipStream_t stream) {
  const float* query  = (const float*)d_in[0];
  const float* i_proj = (const float*)d_in[1];
  const float* in_w   = (const float*)d_in[2];
  const float* in_b   = (const float*)d_in[3];
  const float* out_w  = (const float*)d_in[4];
  const float* out_b  = (const float*)d_in[5];
  const float* bias_k = (const float*)d_in[6];
  const float* bias_v = (const float*)d_in[7];
  float* out = (float*)d_out;

  char* ws = (char*)d_ws;
  bf16* qbf_in = (bf16*)(ws + WS_QBF_IN);
  bf16* w_bf   = (bf16*)(ws + WS_WBF);
  bf16* outwbf = (bf16*)(ws + WS_OUTWBF);
  bf16* q_bf   = (bf16*)(ws + WS_Q);
  bf16* k_bf   = (bf16*)(ws + WS_K);
  bf16* v_bf   = (bf16*)(ws + WS_V);
  bf16* vT     = (bf16*)(ws + WS_VT);
  bf16* kT     = (bf16*)(ws + WS_KT);
  bf16* ktvT   = (bf16*)(ws + WS_KTV);
  bf16* aw_raw = (bf16*)(ws + WS_V);    // reuses v_bf+vT (33.5MB) after ktv
  float* aw_last = (float*)(ws + WS_AWLAST);
  float* vcs     = (float*)(ws + WS_VCS);
  unsigned* mm   = (unsigned*)(ws + WS_MM);
  bf16* A2 = qbf_in;  // reuse: qbf_in dead after proj GEMM

  float* out_attn  = out;                       // (1024,16,512)
  float* out_awavg = out + 8388608L;            // (16,1024,1025)
  float* out_wret  = out + 25182208L;           // (3,512,512)

  prep_all_kernel<<<4096, 256, 0, stream>>>(query, qbf_in, in_w, i_proj, out_w,
                                            w_bf, outwbf, out_wret, mm);
  gemm_kernel<0, 3><<<dim3(12, 128), 256, 0, stream>>>(qbf_in, w_bf, in_b,
                                                       q_bf, k_bf, v_bf, nullptr);
  transpose_kv_kernel<<<dim3(16, 128, 2), 256, 0, stream>>>(k_bf, v_bf, kT, vT);
  reduce_small_kernel<<<640, 256, 0, stream>>>(vT, bias_v, vcs, q_bf, bias_k, aw_last, mm);
  ktv_kernel<<<128, 256, 0, stream>>>(kT, vT, ktvT);           // frees vT/v_bf region
  awsum_gemm_kernel<<<1024, 256, 0, stream>>>(q_bf, k_bf, aw_raw, mm);
  rescale_kernel<<<65600, 256, 0, stream>>>(aw_raw, out_awavg, aw_last, mm);
  qattn_kernel<<<dim3(16, 2, 16), 256, 0, stream>>>(q_bf, ktvT, aw_last, vcs, bias_v, mm, A2);
  gemm_kernel<1, 2><<<dim3(4, 128), 256, 0, stream>>>(A2, outwbf, out_b,
                                                      nullptr, nullptr, nullptr, out_attn);
}